// Round 1
// 1079.321 us; speedup vs baseline: 1.4114x; 1.4114x over previous
//
#include <hip/hip_runtime.h>

// SimpleRNN: B=4096, K=512, U=3, P=5, H=128, L=32, N_SUB=10
// 256 blocks x 512 threads (8 waves), 16 batch rows/block, 1 block/CU.
// "T-scheme": all GEMMs computed transposed (weights as MFMA A-operand,
// activations as B-operand) so D has batch-row in lane&15 and out-col in
// regs. LDS fragment buffers are lane-major: consumer lane l reads its 16B
// block at l*16 (conflict-free b128); producers write one ds_write_b64.
// Theta emerges row-per-lane (quad0=kf, quad1=kr) -> ds_swizzle xor16.
//
// R1: RK4 restructured. _rhs is LINEAR in y: dy = A(theta) y with
// A = B*C (B 5x4 incidence, C 4x5 flux). One RK4 substep == y <- max(M y, 0)
// with M = I + hA + h^2/2 A^2 + h^3/6 A^3 + h^4/24 A^4 (exact same
// polynomial as the staged evaluation; clamp kept per substep). Powers
// collapse via T = C*B (4x4 tridiag: T[j][j-1]=kf_j, T[j][j]=-(kf_j+kr_j),
// T[j][j+1]=kr_j): M = I5 + B*P*C, P = h(I + h/2 T(I + h/3 T(I + h/4 T))).
// M is built once per step (ILP-rich, ~180 inst), then 10 x (25 fma + 5 max)
// instead of ~970 serial-dependent RHS instructions.
// Also: v_cvt_pk_bf16_f32 (1 inst / 2 values, RNE) replaces manual f2bf on
// the hot packs (h-stage, af build, silu x-stage).

#define KSTEPS 512
#define NTH 512

typedef short s16x8 __attribute__((ext_vector_type(8)));
typedef short s16x4 __attribute__((ext_vector_type(4)));
typedef float f32x4 __attribute__((ext_vector_type(4)));

__device__ __forceinline__ unsigned short f2bf(float f) {
  union { float f; unsigned u; } v; v.f = f;
  unsigned r = v.u + 0x7FFFu + ((v.u >> 16) & 1u);  // RNE
  return (unsigned short)(r >> 16);
}
__device__ __forceinline__ unsigned cvt2bf(float lo, float hi) {
  unsigned r;
  asm("v_cvt_pk_bf16_f32 %0, %1, %2" : "=v"(r) : "v"(lo), "v"(hi));
  return r;
}
__device__ __forceinline__ float ex2(float x) {
#if __has_builtin(__builtin_amdgcn_exp2f)
  return __builtin_amdgcn_exp2f(x);
#else
  return exp2f(x);
#endif
}
__device__ __forceinline__ float rcp_(float x) {
#if __has_builtin(__builtin_amdgcn_rcpf)
  return __builtin_amdgcn_rcpf(x);
#else
  return 1.0f / x;
#endif
}
__device__ __forceinline__ float sigm(float x) {
  return rcp_(1.0f + ex2(-1.44269504088896f * x));
}
__device__ __forceinline__ float tanh_(float x) {
  return fmaf(2.0f, rcp_(1.0f + ex2(-2.88539008177793f * x)), -1.0f);
}
__device__ __forceinline__ f32x4 splat4(float v) { f32x4 r = {v, v, v, v}; return r; }
__device__ __forceinline__ f32x4 MFMA(s16x8 a, s16x8 b, f32x4 c) {
  return __builtin_amdgcn_mfma_f32_16x16x32_bf16(a, b, c, 0, 0, 0);
}
__device__ __forceinline__ s16x8 bfrag_g(const float* __restrict__ src8) {
  s16x8 r;
#pragma unroll
  for (int j = 0; j < 8; ++j) r[j] = (short)f2bf(src8[j]);
  return r;
}
__device__ __forceinline__ float swz16(float x) {  // lane <- lane^16
  return __int_as_float(__builtin_amdgcn_ds_swizzle(__float_as_int(x), 0x401F));
}

__global__ __launch_bounds__(NTH, 2) void rnn_scan_kernel(
    const float* __restrict__ y0, const float* __restrict__ u_seq,
    const float* __restrict__ dt_seq, const float* __restrict__ lift_W,
    const float* __restrict__ lift_b, const float* __restrict__ W_ih,
    const float* __restrict__ W_hh, const float* __restrict__ b_ih,
    const float* __restrict__ b_hh, const float* __restrict__ head_W,
    const float* __restrict__ head_b, const float* __restrict__ jumpW,
    float* __restrict__ y_out, float* __restrict__ th_out) {
  // lane-major fragment buffers: block (s*64 + q*16 + row) of 8 shorts holds
  // act[row][s*32 + q*8 .. +7]; consumer lane l frag s reads block s*64+l.
  __shared__ __align__(16) unsigned short s_Ah[4096];  // h: k=128 -> 4 frags
  __shared__ __align__(16) unsigned short s_Ax[1024];  // x: k=32  -> 1 frag
  __shared__ __align__(16) float s_thr[2][16][8];      // theta ring
  __shared__ __align__(16) float s_yr[2][16][8];       // y ring (padded)

  const int tid = threadIdx.x;
  const int w = tid >> 6;      // wave 0..7; wave 7 = critical wave
  const int lane = tid & 63;
  const int quad = lane >> 4;
  const int col = lane & 15;   // = batch row in the T-scheme
  const int r0 = blockIdx.x << 4;

  s16x8 zf;
#pragma unroll
  for (int j = 0; j < 8; ++j) zf[j] = 0;

  // ---- weight A-frags: A[m=out-col@lane&15][k=quad*8+j] ----
  s16x8 bih_r = bfrag_g(&W_ih[(w * 16 + col) * 32 + quad * 8]);
  s16x8 bih_z = bfrag_g(&W_ih[((8 + w) * 16 + col) * 32 + quad * 8]);
  s16x8 bih_n = bfrag_g(&W_ih[((16 + w) * 16 + col) * 32 + quad * 8]);
  s16x8 bhh_r[4], bhh_z[4], bhh_n[4], bhd[4];
#pragma unroll
  for (int s = 0; s < 4; ++s) {
    bhh_r[s] = bfrag_g(&W_hh[(w * 16 + col) * 128 + s * 32 + quad * 8]);
    bhh_z[s] = bfrag_g(&W_hh[((8 + w) * 16 + col) * 128 + s * 32 + quad * 8]);
    bhh_n[s] = bfrag_g(&W_hh[((16 + w) * 16 + col) * 128 + s * 32 + quad * 8]);
    bhd[s] = (col < 8) ? bfrag_g(&head_W[col * 128 + s * 32 + quad * 8]) : zf;
  }
  s16x8 blft0 = (quad == 0) ? bfrag_g(&lift_W[col * 8]) : zf;
  s16x8 blft1 = (quad == 0) ? bfrag_g(&lift_W[(16 + col) * 8]) : zf;

  // ---- per-(quad,i) biases (out-col dim now lives in regs+quad) ----
  f32x4 brz_r, brz_z, bn_iv, bn_hv, lbv0, lbv1, hbv;
#pragma unroll
  for (int i = 0; i < 4; ++i) {
    int g = w * 16 + quad * 4 + i;
    brz_r[i] = b_ih[g] + b_hh[g];
    brz_z[i] = b_ih[128 + g] + b_hh[128 + g];
    bn_iv[i] = b_ih[256 + g];
    bn_hv[i] = b_hh[256 + g];
    lbv0[i] = lift_b[quad * 4 + i];
    lbv1[i] = lift_b[16 + quad * 4 + i];
    hbv[i] = (quad < 2) ? head_b[quad * 4 + i] : 0.0f;
  }
  float J[15];
#pragma unroll
  for (int i = 0; i < 15; ++i) J[i] = jumpW[i];

  // producer LDS byte offsets
  const int hwoff = (((w >> 1) * 64 + ((w & 1) * 2 + (quad >> 1)) * 16 + col) << 4) +
                    ((quad & 1) << 3);
  const int xw0 = ((((quad >> 1)) * 16 + col) << 4) + ((quad & 1) << 3);
  const int xw1 = (((2 + (quad >> 1)) * 16 + col) << 4) + ((quad & 1) << 3);

  // persistent state
  f32x4 ar = brz_r, az = brz_z, angi = bn_iv, angh = bn_hv;
  f32x4 h_reg = splat4(0.0f);
  float y[5] = {0.f, 0.f, 0.f, 0.f, 0.f};
  float uc0 = 0.f, uc1 = 0.f, uc2 = 0.f, dtc = 0.f;
  float un0 = 0.f, un1 = 0.f, un2 = 0.f, dtn = 0.f;

  // ---- prologue: wave 7 builds x(0) ----
  if (w == 7) {
    if (quad == 0) {
      const float* yp = &y0[(r0 + col) * 5];
#pragma unroll
      for (int i = 0; i < 5; ++i) y[i] = yp[i] + 0.01f;
      const float* up = &u_seq[((size_t)(r0 + col) * KSTEPS) * 3];
      uc0 = up[0]; uc1 = up[1]; uc2 = up[2];
      dtc = dt_seq[(size_t)(r0 + col) * KSTEPS];
    }
    s16x8 af = zf;
    if (quad == 0) {
      union { s16x8 v; unsigned u[4]; } afu;
      afu.u[0] = cvt2bf(uc0, uc1);
      afu.u[1] = cvt2bf(uc2, y[0]);
      afu.u[2] = cvt2bf(y[1], y[2]);
      afu.u[3] = cvt2bf(y[3], y[4]);
      af = afu.v;
    }
    f32x4 x0 = MFMA(blft0, af, lbv0);
    f32x4 x1 = MFMA(blft1, af, lbv1);
    f32x4 s0, s1;
#pragma unroll
    for (int i = 0; i < 4; ++i) {
      float v0 = x0[i]; s0[i] = v0 * sigm(v0);
      float v1 = x1[i]; s1[i] = v1 * sigm(v1);
    }
    uint2 xp0, xp1;
    xp0.x = cvt2bf(s0[0], s0[1]); xp0.y = cvt2bf(s0[2], s0[3]);
    xp1.x = cvt2bf(s1[0], s1[1]); xp1.y = cvt2bf(s1[2], s1[3]);
    *(uint2*)((char*)s_Ax + xw0) = xp0;
    *(uint2*)((char*)s_Ax + xw1) = xp1;
  }
  __syncthreads();  // B_x(0)

#pragma unroll 1
  for (int k = 0; k < KSTEPS; ++k) {
    // ======== phase 1: gi + gates + h stage (all waves) ========
    {
      s16x8 xf = *(const s16x8*)((const char*)s_Ax + lane * 16);
      ar = MFMA(bih_r, xf, ar);
      az = MFMA(bih_z, xf, az);
      angi = MFMA(bih_n, xf, angi);
    }
    if (w == 7 && quad == 0) {  // prefetch u/dt for step k+1
      int kn = (k + 1 < KSTEPS) ? k + 1 : KSTEPS - 1;
      const float* up = &u_seq[((size_t)(r0 + col) * KSTEPS + kn) * 3];
      un0 = up[0]; un1 = up[1]; un2 = up[2];
      dtn = dt_seq[(size_t)(r0 + col) * KSTEPS + kn];
    }
    {
      f32x4 hf;
#pragma unroll
      for (int i = 0; i < 4; ++i) {
        float r = sigm(ar[i]);
        float z = sigm(az[i]);
        float n = tanh_(fmaf(r, angh[i], angi[i]));
        float hn = fmaf(z, h_reg[i] - n, n);
        h_reg[i] = hn;
        hf[i] = hn;
      }
      uint2 hp;
      hp.x = cvt2bf(hf[0], hf[1]);
      hp.y = cvt2bf(hf[2], hf[3]);
      *(uint2*)((char*)s_Ah + hwoff) = hp;  // one b64, ~4-way (free-ish)
    }
    ar = brz_r; az = brz_z; angi = bn_iv; angh = bn_hv;  // reset for k+1
    __syncthreads();  // B_h

    // ======== phase 2 ========
    s16x8 ah[4];
#pragma unroll
    for (int s = 0; s < 4; ++s)
      ah[s] = *(const s16x8*)((const char*)s_Ah + (s * 64 + lane) * 16);

    if (w == 7) {
      // headT: D[m=c][n=row] -> lane(col=row, quad<2) holds th[quad*4+i]
      f32x4 hd0 = MFMA(bhd[0], ah[0], hbv);
      f32x4 hd1 = MFMA(bhd[1], ah[1], splat4(0.0f));
      hd0 = MFMA(bhd[2], ah[2], hd0);
      hd1 = MFMA(bhd[3], ah[3], hd1);
      // own gh(k+1) overlaps the head->theta latency
#pragma unroll
      for (int s = 0; s < 4; ++s) {
        ar = MFMA(bhh_r[s], ah[s], ar);
        az = MFMA(bhh_z[s], ah[s], az);
        angh = MFMA(bhh_n[s], ah[s], angh);
      }
      f32x4 hd = hd0 + hd1;
      f32x4 tv;
#pragma unroll
      for (int i = 0; i < 4; ++i) tv[i] = fmaf(2.99f, sigm(hd[i]), 0.01f);
      const int slot = k & 1;
      if (quad < 2) *(f32x4*)&s_thr[slot][col][quad * 4] = tv;
      // quad0: own tv = kf1..4, swizzled (lane^16) tv = kr1..4
      float F0 = tv[0], F1 = tv[1], F2 = tv[2], F3 = tv[3];
      float R0 = swz16(tv[0]), R1 = swz16(tv[1]), R2 = swz16(tv[2]), R3 = swz16(tv[3]);
      // jump + linear-RK4 (uniform execution; valid on quad0, benign elsewhere)
#pragma unroll
      for (int i = 0; i < 5; ++i)
        y[i] += uc0 * J[i] + uc1 * J[5 + i] + uc2 * J[10 + i];
      const float hs = dtc * 0.1f;

      // ---- build M = I5 + B*P*C once (exact RK4 polynomial) ----
      // T = C*B (4x4 tridiag): diag TDj=-(Fj+Rj), sub T[j][j-1]=Fj, sup T[j][j+1]=Rj
      const float TD0 = -(F0 + R0), TD1 = -(F1 + R1), TD2 = -(F2 + R2), TD3 = -(F3 + R3);
      const float c4 = 0.25f * hs, c3 = hs * (1.0f / 3.0f), c2 = 0.5f * hs;
      // Z3 = I + c4*T (tridiag)
      const float d30 = fmaf(c4, TD0, 1.f), d31 = fmaf(c4, TD1, 1.f);
      const float d32 = fmaf(c4, TD2, 1.f), d33 = fmaf(c4, TD3, 1.f);
      const float l31 = c4 * F1, l32 = c4 * F2, l33 = c4 * F3;
      const float u30 = c4 * R0, u31 = c4 * R1, u32 = c4 * R2;
      // W3 = T*Z3 (band 2)
      const float w300 = fmaf(TD0, d30, R0 * l31);
      const float w301 = fmaf(TD0, u30, R0 * d31);
      const float w302 = R0 * u31;
      const float w310 = fmaf(F1, d30, TD1 * l31);
      const float w311 = fmaf(F1, u30, fmaf(TD1, d31, R1 * l32));
      const float w312 = fmaf(TD1, u31, R1 * d32);
      const float w313 = R1 * u32;
      const float w320 = F2 * l31;
      const float w321 = fmaf(F2, d31, TD2 * l32);
      const float w322 = fmaf(F2, u31, fmaf(TD2, d32, R2 * l33));
      const float w323 = fmaf(TD2, u32, R2 * d33);
      const float w331 = F3 * l32;
      const float w332 = fmaf(F3, d32, TD3 * l33);
      const float w333 = fmaf(F3, u32, TD3 * d33);
      // Z2 = I + c3*W3 (band 2; [0][3]=[3][0]=0)
      const float e20 = fmaf(c3, w300, 1.f), e21 = fmaf(c3, w311, 1.f);
      const float e22 = fmaf(c3, w322, 1.f), e23 = fmaf(c3, w333, 1.f);
      const float a201 = c3 * w301, a202 = c3 * w302;
      const float a210 = c3 * w310, a212 = c3 * w312, a213 = c3 * w313;
      const float a220 = c3 * w320, a221 = c3 * w321, a223 = c3 * w323;
      const float a231 = c3 * w331, a232 = c3 * w332;
      // W2 = T*Z2 (full 4x4)
      const float w200 = fmaf(TD0, e20, R0 * a210);
      const float w201 = fmaf(TD0, a201, R0 * e21);
      const float w202 = fmaf(TD0, a202, R0 * a212);
      const float w203 = R0 * a213;
      const float w210 = fmaf(F1, e20, fmaf(TD1, a210, R1 * a220));
      const float w211 = fmaf(F1, a201, fmaf(TD1, e21, R1 * a221));
      const float w212 = fmaf(F1, a202, fmaf(TD1, a212, R1 * e22));
      const float w213 = fmaf(TD1, a213, R1 * a223);
      const float w220 = fmaf(F2, a210, TD2 * a220);
      const float w221 = fmaf(F2, e21, fmaf(TD2, a221, R2 * a231));
      const float w222 = fmaf(F2, a212, fmaf(TD2, e22, R2 * a232));
      const float w223 = fmaf(F2, a213, fmaf(TD2, a223, R2 * e23));
      const float w230 = F3 * a220;
      const float w231 = fmaf(F3, a221, TD3 * a231);
      const float w232 = fmaf(F3, e22, TD3 * a232);
      const float w233 = fmaf(F3, a223, TD3 * e23);
      // Z1 = I + c2*W2 (full)
      const float z100 = fmaf(c2, w200, 1.f), z101 = c2 * w201, z102 = c2 * w202, z103 = c2 * w203;
      const float z110 = c2 * w210, z111 = fmaf(c2, w211, 1.f), z112 = c2 * w212, z113 = c2 * w213;
      const float z120 = c2 * w220, z121 = c2 * w221, z122 = fmaf(c2, w222, 1.f), z123 = c2 * w223;
      const float z130 = c2 * w230, z131 = c2 * w231, z132 = c2 * w232, z133 = fmaf(c2, w233, 1.f);
      // PC = (hs*Z1)*C, C[l][l]=F_l, C[l][l+1]=-R_l (hs folded into FH/RH)
      const float FH0 = hs * F0, FH1 = hs * F1, FH2 = hs * F2, FH3 = hs * F3;
      const float RH0 = hs * R0, RH1 = hs * R1, RH2 = hs * R2, RH3 = hs * R3;
      const float pc00 = z100 * FH0;
      const float pc01 = fmaf(z101, FH1, -(z100 * RH0));
      const float pc02 = fmaf(z102, FH2, -(z101 * RH1));
      const float pc03 = fmaf(z103, FH3, -(z102 * RH2));
      const float pc04 = -(z103 * RH3);
      const float pc10 = z110 * FH0;
      const float pc11 = fmaf(z111, FH1, -(z110 * RH0));
      const float pc12 = fmaf(z112, FH2, -(z111 * RH1));
      const float pc13 = fmaf(z113, FH3, -(z112 * RH2));
      const float pc14 = -(z113 * RH3);
      const float pc20 = z120 * FH0;
      const float pc21 = fmaf(z121, FH1, -(z120 * RH0));
      const float pc22 = fmaf(z122, FH2, -(z121 * RH1));
      const float pc23 = fmaf(z123, FH3, -(z122 * RH2));
      const float pc24 = -(z123 * RH3);
      const float pc30 = z130 * FH0;
      const float pc31 = fmaf(z131, FH1, -(z130 * RH0));
      const float pc32 = fmaf(z132, FH2, -(z131 * RH1));
      const float pc33 = fmaf(z133, FH3, -(z132 * RH2));
      const float pc34 = -(z133 * RH3);
      // M = I5 + B*PC (B row0=-PC0, rowi=PC(i-1)-PCi, row4=PC3)
      const float m00 = 1.0f - pc00, m01 = -pc01, m02 = -pc02, m03 = -pc03, m04 = -pc04;
      const float m10 = pc00 - pc10, m11 = 1.0f + (pc01 - pc11), m12 = pc02 - pc12,
                  m13 = pc03 - pc13, m14 = pc04 - pc14;
      const float m20 = pc10 - pc20, m21 = pc11 - pc21, m22 = 1.0f + (pc12 - pc22),
                  m23 = pc13 - pc23, m24 = pc14 - pc24;
      const float m30 = pc20 - pc30, m31 = pc21 - pc31, m32 = pc22 - pc32,
                  m33 = 1.0f + (pc23 - pc33), m34 = pc24 - pc34;
      const float m40 = pc30, m41 = pc31, m42 = pc32, m43 = pc33, m44 = 1.0f + pc34;
      // ---- 10 substeps: y <- max(M y, 0) ----
#pragma unroll
      for (int ss = 0; ss < 10; ++ss) {
        float n0 = m00 * y[0];
        n0 = fmaf(m01, y[1], n0); n0 = fmaf(m02, y[2], n0);
        n0 = fmaf(m03, y[3], n0); n0 = fmaf(m04, y[4], n0);
        float n1 = m10 * y[0];
        n1 = fmaf(m11, y[1], n1); n1 = fmaf(m12, y[2], n1);
        n1 = fmaf(m13, y[3], n1); n1 = fmaf(m14, y[4], n1);
        float n2 = m20 * y[0];
        n2 = fmaf(m21, y[1], n2); n2 = fmaf(m22, y[2], n2);
        n2 = fmaf(m23, y[3], n2); n2 = fmaf(m24, y[4], n2);
        float n3 = m30 * y[0];
        n3 = fmaf(m31, y[1], n3); n3 = fmaf(m32, y[2], n3);
        n3 = fmaf(m33, y[3], n3); n3 = fmaf(m34, y[4], n3);
        float n4 = m40 * y[0];
        n4 = fmaf(m41, y[1], n4); n4 = fmaf(m42, y[2], n4);
        n4 = fmaf(m43, y[3], n4); n4 = fmaf(m44, y[4], n4);
        y[0] = fmaxf(n0, 0.0f);
        y[1] = fmaxf(n1, 0.0f);
        y[2] = fmaxf(n2, 0.0f);
        y[3] = fmaxf(n3, 0.0f);
        y[4] = fmaxf(n4, 0.0f);
      }
      if (quad == 0) {
        *(f32x4*)&s_yr[slot][col][0] = *(const f32x4*)&y[0];
        s_yr[slot][col][4] = y[4];
      }
      // feat(k+1) -> liftT -> silu -> x stage
      if (k + 1 < KSTEPS) {
        s16x8 af = zf;
        if (quad == 0) {
          union { s16x8 v; unsigned u[4]; } afu;
          afu.u[0] = cvt2bf(un0, un1);
          afu.u[1] = cvt2bf(un2, y[0]);
          afu.u[2] = cvt2bf(y[1], y[2]);
          afu.u[3] = cvt2bf(y[3], y[4]);
          af = afu.v;
        }
        f32x4 x0 = MFMA(blft0, af, lbv0);
        f32x4 x1 = MFMA(blft1, af, lbv1);
        f32x4 s0, s1;
#pragma unroll
        for (int i = 0; i < 4; ++i) {
          float v0 = x0[i]; s0[i] = v0 * sigm(v0);
          float v1 = x1[i]; s1[i] = v1 * sigm(v1);
        }
        uint2 xp0, xp1;
        xp0.x = cvt2bf(s0[0], s0[1]); xp0.y = cvt2bf(s0[2], s0[3]);
        xp1.x = cvt2bf(s1[0], s1[1]); xp1.y = cvt2bf(s1[2], s1[3]);
        *(uint2*)((char*)s_Ax + xw0) = xp0;
        *(uint2*)((char*)s_Ax + xw1) = xp1;
      }
      uc0 = un0; uc1 = un1; uc2 = un2; dtc = dtn;
    } else {
      // gh(k+1) for this wave's tile (in wave-7's shadow)
#pragma unroll
      for (int s = 0; s < 4; ++s) {
        ar = MFMA(bhh_r[s], ah[s], ar);
        az = MFMA(bhh_z[s], ah[s], az);
        angh = MFMA(bhh_n[s], ah[s], angh);
      }
      if (w == 0 && k > 0) {  // store step k-1 outputs from the ring
        const int km = k - 1, slot = km & 1;
#pragma unroll
        for (int rep = 0; rep < 2; ++rep) {
          int idx = lane + rep * 64;
          int row = idx >> 3, c = idx & 7;
          th_out[((size_t)(r0 + row) * KSTEPS + km) * 8 + c] = s_thr[slot][row][c];
        }
        {
          int idx = lane;
          int row = idx / 5, c = idx - row * 5;
          y_out[((size_t)(r0 + row) * KSTEPS + km) * 5 + c] = s_yr[slot][row][c];
        }
        if (lane < 16) {
          int idx = 64 + lane;
          int row = idx / 5, c = idx - row * 5;
          y_out[((size_t)(r0 + row) * KSTEPS + km) * 5 + c] = s_yr[slot][row][c];
        }
      }
    }
    __syncthreads();  // B_x: x(k+1) staged, s_Ah reusable
  }

  // flush step-511 outputs
  if (w == 0) {
    const int km = KSTEPS - 1, slot = km & 1;
#pragma unroll
    for (int rep = 0; rep < 2; ++rep) {
      int idx = lane + rep * 64;
      int row = idx >> 3, c = idx & 7;
      th_out[((size_t)(r0 + row) * KSTEPS + km) * 8 + c] = s_thr[slot][row][c];
    }
    {
      int idx = lane;
      int row = idx / 5, c = idx - row * 5;
      y_out[((size_t)(r0 + row) * KSTEPS + km) * 5 + c] = s_yr[slot][row][c];
    }
    if (lane < 16) {
      int idx = 64 + lane;
      int row = idx / 5, c = idx - row * 5;
      y_out[((size_t)(r0 + row) * KSTEPS + km) * 5 + c] = s_yr[slot][row][c];
    }
  }
}

extern "C" void kernel_launch(void* const* d_in, const int* in_sizes, int n_in,
                              void* d_out, int out_size, void* d_ws, size_t ws_size,
                              hipStream_t stream) {
  const float* y0 = (const float*)d_in[0];
  const float* u_seq = (const float*)d_in[1];
  const float* dt_seq = (const float*)d_in[2];
  const float* lift_W = (const float*)d_in[3];
  const float* lift_b = (const float*)d_in[4];
  const float* W_ih = (const float*)d_in[5];
  const float* W_hh = (const float*)d_in[6];
  const float* b_ih = (const float*)d_in[7];
  const float* b_hh = (const float*)d_in[8];
  const float* head_W = (const float*)d_in[9];
  const float* head_b = (const float*)d_in[10];
  const float* jumpW = (const float*)d_in[11];

  float* y_out = (float*)d_out;                    // (4096, 512, 5)
  float* th_out = y_out + (size_t)4096 * 512 * 5;  // (4096, 512, 8)

  rnn_scan_kernel<<<dim3(256), dim3(NTH), 0, stream>>>(
      y0, u_seq, dt_seq, lift_W, lift_b, W_ih, W_hh, b_ih, b_hh, head_W,
      head_b, jumpW, y_out, th_out);
}